// Round 6
// baseline (1669.419 us; speedup 1.0000x reference)
//
#include <hip/hip_runtime.h>
#include <hip/hip_bf16.h>

typedef __attribute__((ext_vector_type(8))) short short8;
typedef __attribute__((ext_vector_type(4))) float float4v;

#if __has_builtin(__builtin_amdgcn_sdot4)
#define DOT4(a, b, c) __builtin_amdgcn_sdot4((int)(a), (int)(b), (c), false)
#else
__device__ __forceinline__ int dot4_(int a, int b, int c) {
  c += (int)(signed char)(a) * (int)(signed char)(b);
  c += (int)(signed char)(a >> 8) * (int)(signed char)(b >> 8);
  c += (int)(signed char)(a >> 16) * (int)(signed char)(b >> 16);
  c += (a >> 24) * (b >> 24);
  return c;
}
#define DOT4(a, b, c) dot4_((int)(a), (int)(b), (c))
#endif

__device__ __forceinline__ float sigmoidf_(float x) {
  return __fdividef(1.f, 1.f + __expf(-x));
}
__device__ __forceinline__ float tanhf_(float x) {
  float e = __expf(2.f * x);
  return 1.f - __fdividef(2.f, e + 1.f);
}
__device__ __forceinline__ float bflo(unsigned int v) {
  return __uint_as_float(v << 16);
}
__device__ __forceinline__ float bfhi(unsigned int v) {
  return __uint_as_float(v & 0xffff0000u);
}

// quad (4-lane) butterflies via DPP quad_perm (VALU, not DS pipe)
template <int CTRL>
__device__ __forceinline__ int qadd_i(int v) {
  return v + __builtin_amdgcn_update_dpp(0, v, CTRL, 0xF, 0xF, true);
}
template <int CTRL>
__device__ __forceinline__ float qmax_f(float v) {
  int r = __builtin_amdgcn_update_dpp(0, __float_as_int(v), CTRL, 0xF, 0xF, true);
  return fmaxf(v, __int_as_float(r));
}
#define XOR1 0xB1  // quad_perm [1,0,3,2]
#define XOR2 0x4E  // quad_perm [2,3,0,1]

// ---------------------------------------------------------------------------
// Kernel A: projected embedding tables.
// Logical col n in [0,2048): dir=n>>10, r=n&1023, gate=r>>8, u=r&255.
// Stored at out[m*2048 + dir*1024 + u*4 + gate]  ([row][dir][unit][i,f,g,o]).
// ---------------------------------------------------------------------------
__global__ __launch_bounds__(256) void proj_gemm(
    const float* __restrict__ A, int rowsA, int Kdim, int col_off,
    const float* __restrict__ wf, const float* __restrict__ wb,
    const float* __restrict__ bf1, const float* __restrict__ bf2,
    const float* __restrict__ bb1, const float* __restrict__ bb2,
    __hip_bfloat16* __restrict__ out, int add_bias) {
  __shared__ __align__(16) __hip_bfloat16 As[64][40];
  __shared__ __align__(16) __hip_bfloat16 Bs[256][40];
  const int tid = threadIdx.x;
  const int m0 = blockIdx.x * 64, n0 = blockIdx.y * 256;
  const int lane = tid & 63, wave = tid >> 6;
  const int quad = lane >> 4, lm = lane & 15;
  float4v acc[16] = {};
  const int ksteps = (Kdim + 31) >> 5;
  const int r = tid >> 2, c0 = (tid & 3) << 3;
  for (int ks = 0; ks < ksteps; ++ks) {
    const int k0 = ks << 5;
#pragma unroll
    for (int e = 0; e < 8; ++e) {
      int kk = k0 + c0 + e;
      float av = (m0 + r < rowsA && kk < Kdim) ? A[(m0 + r) * Kdim + kk] : 0.f;
      As[r][c0 + e] = __float2bfloat16(av);
    }
    {
      int n = n0 + tid;
      const float* __restrict__ wrow =
          (n < 1024) ? (wf + n * 450 + col_off) : (wb + (n - 1024) * 450 + col_off);
#pragma unroll
      for (int e2 = 0; e2 < 16; ++e2) {
        int kk = k0 + e2 * 2;
        float b0 = 0.f, b1 = 0.f;
        if (kk < Kdim) {  // Kdim even: pairs never straddle
          float2 v = *(const float2*)(wrow + kk);
          b0 = v.x;
          b1 = v.y;
        }
        Bs[tid][e2 * 2] = __float2bfloat16(b0);
        Bs[tid][e2 * 2 + 1] = __float2bfloat16(b1);
      }
    }
    __syncthreads();
    short8 af = *(const short8*)(&As[wave * 16 + lm][quad * 8]);
#pragma unroll
    for (int t = 0; t < 16; ++t) {
      short8 bf = *(const short8*)(&Bs[t * 16 + lm][quad * 8]);
      acc[t] = __builtin_amdgcn_mfma_f32_16x16x32_bf16(af, bf, acc[t], 0, 0, 0);
    }
    __syncthreads();
  }
#pragma unroll
  for (int t = 0; t < 16; ++t) {
#pragma unroll
    for (int rr = 0; rr < 4; ++rr) {
      int m = m0 + wave * 16 + quad * 4 + rr;
      int col = n0 + t * 16 + lm;
      if (m < rowsA) {
        float v = acc[t][rr];
        if (add_bias)
          v += (col < 1024) ? (bf1[col] + bf2[col]) : (bb1[col - 1024] + bb2[col - 1024]);
        int dir = col >> 10, r2 = col & 1023;
        int gate = r2 >> 8, u = r2 & 255;
        out[m * 2048 + dir * 1024 + u * 4 + gate] = __float2bfloat16(v);
      }
    }
  }
}

// ---------------------------------------------------------------------------
// Kernel B: BiLSTM recurrence, int8 dot4, 1024 threads/chain.
// Quad q owns unit q (4 gate rows i,f,g,o); lane e holds K-slice [64e,64e+64).
// W = 4 rows x 16 uints = 64 VGPRs; live set ~104.
// OCCUPANCY PIN: static LDS is inflated past 80 KiB (force_lds) so only ONE
// 1024-thr WG fits per CU -> compiler budgets 4 waves/EU = 128 VGPRs instead
// of the 2-WG/CU default (8 waves/EU = 64 VGPRs, which spilled 437 MB of
// scratch in R4/R5). Grid=256=#CUs, so runtime occupancy is unchanged.
// ---------------------------------------------------------------------------
__global__ __attribute__((amdgpu_flat_work_group_size(1024, 1024),
                          amdgpu_waves_per_eu(4, 4))) void lstm_kernel(
    const float* __restrict__ whh_f, const float* __restrict__ whh_b,
    const int* __restrict__ x, const int* __restrict__ ptags, const int* __restrict__ gtags,
    const char* __restrict__ char_proj, const char* __restrict__ pin_proj,
    const char* __restrict__ tag_proj, __hip_bfloat16* __restrict__ h_out) {
  __shared__ __align__(16) int4 sidx[512];            // byte offsets per t
  __shared__ __align__(16) signed char hbuf[2][256];  // h int8, double-buffered
  __shared__ __align__(16) int force_lds[19200];      // 76800 B occupancy pin

  const int tid = threadIdx.x;
  const int q = tid >> 2, e = tid & 3;
  const int chain = blockIdx.x;
  const int dir = chain >> 7;
  const int b = chain & 127;
  const float* __restrict__ whh = dir ? whh_b : whh_f;

  // keep force_lds referenced (write here, opaquely-guarded read at the end)
  force_lds[tid] = tid;

  // stage index byte-offsets (table row pitch = 2048 bf16 = 4096 B)
  if (tid < 512)
    sidx[tid] = make_int4(x[b * 512 + tid] * 4096, ptags[b * 512 + tid] * 4096,
                          gtags[b * 512 + tid] * 4096, 0);
  if (tid < 16) ((int4*)hbuf[0])[tid] = make_int4(0, 0, 0, 0);

  // ---- int8-quantize weight slice: 4 gate rows of unit q, K in [64e,64e+64) ----
  unsigned int W[4][16];
  float sc[4];
#pragma unroll
  for (int gg = 0; gg < 4; ++gg) {
    const float* __restrict__ wr = whh + (gg * 256 + q) * 256 + e * 64;
    float mx = 0.f;
#pragma unroll
    for (int k4 = 0; k4 < 16; ++k4) {
      float4 v = ((const float4*)wr)[k4];
      mx = fmaxf(mx, fmaxf(fmaxf(fabsf(v.x), fabsf(v.y)), fmaxf(fabsf(v.z), fabsf(v.w))));
    }
    mx = qmax_f<XOR1>(mx);
    mx = qmax_f<XOR2>(mx);  // full-row max across the 4 k-slices
    float inv = (mx > 0.f) ? __fdividef(127.f, mx) : 0.f;
    sc[gg] = (mx > 0.f) ? (mx / (127.f * 127.f)) : 0.f;  // combined w*h dequant scale
#pragma unroll
    for (int k4 = 0; k4 < 16; ++k4) {
      float4 v = ((const float4*)wr)[k4];
      int b0 = (int)rintf(v.x * inv), b1 = (int)rintf(v.y * inv);
      int b2 = (int)rintf(v.z * inv), b3 = (int)rintf(v.w * inv);
      W[gg][k4] = (unsigned int)((b0 & 0xff) | ((b1 & 0xff) << 8) | ((b2 & 0xff) << 16) |
                                 ((b3 & 0xff) << 24));
    }
  }
  __syncthreads();

  const int pre_off = dir * 2048 + q * 8;  // bytes within a table row
  float cst = 0.f;

  // prefetch step 0 pre-gates (e==0 lanes)
  int t_cur = dir ? 511 : 0;
  uint2 pc = {}, pp = {}, pt = {};
  if (e == 0) {
    int4 ix = sidx[t_cur];
    pc = *(const uint2*)(char_proj + ix.x + pre_off);
    pp = *(const uint2*)(pin_proj + ix.y + pre_off);
    pt = *(const uint2*)(tag_proj + ix.z + pre_off);
  }

  for (int s = 0; s < 512; ++s) {
    const int t = t_cur;
    const uint2 cv = pc, pv = pp, gv = pt;
    const int tn = dir ? (t > 0 ? t - 1 : 0) : (t < 511 ? t + 1 : 511);
    t_cur = tn;

    // h slice (64 int8 = 4 x b128), buffer parity = s
    const uint4* hv = (const uint4*)(&hbuf[s & 1][e * 64]);
    uint4 H0 = hv[0], H1 = hv[1], H2 = hv[2], H3 = hv[3];

    // prefetch next step's pre-gates
    if (e == 0) {
      int4 ix = sidx[tn];
      pc = *(const uint2*)(char_proj + ix.x + pre_off);
      pp = *(const uint2*)(pin_proj + ix.y + pre_off);
      pt = *(const uint2*)(tag_proj + ix.z + pre_off);
    }

    int acc[4];
#pragma unroll
    for (int gg = 0; gg < 4; ++gg) {
      int a = 0;
      a = DOT4(W[gg][0], H0.x, a);
      a = DOT4(W[gg][1], H0.y, a);
      a = DOT4(W[gg][2], H0.z, a);
      a = DOT4(W[gg][3], H0.w, a);
      a = DOT4(W[gg][4], H1.x, a);
      a = DOT4(W[gg][5], H1.y, a);
      a = DOT4(W[gg][6], H1.z, a);
      a = DOT4(W[gg][7], H1.w, a);
      a = DOT4(W[gg][8], H2.x, a);
      a = DOT4(W[gg][9], H2.y, a);
      a = DOT4(W[gg][10], H2.z, a);
      a = DOT4(W[gg][11], H2.w, a);
      a = DOT4(W[gg][12], H3.x, a);
      a = DOT4(W[gg][13], H3.y, a);
      a = DOT4(W[gg][14], H3.z, a);
      a = DOT4(W[gg][15], H3.w, a);
      acc[gg] = a;
    }
    // quad butterfly: all 4 lanes get full-K sums
#pragma unroll
    for (int gg = 0; gg < 4; ++gg) {
      int v = qadd_i<XOR1>(acc[gg]);
      acc[gg] = qadd_i<XOR2>(v);
    }

    if (e == 0) {
      // pre-gates: (i,f) in .x, (g,o) in .y of each table's uint2
      float gi = bflo(cv.x) + bflo(pv.x) + bflo(gv.x) + (float)acc[0] * sc[0];
      float gf = bfhi(cv.x) + bfhi(pv.x) + bfhi(gv.x) + (float)acc[1] * sc[1];
      float gg_ = bflo(cv.y) + bflo(pv.y) + bflo(gv.y) + (float)acc[2] * sc[2];
      float go = bfhi(cv.y) + bfhi(pv.y) + bfhi(gv.y) + (float)acc[3] * sc[3];
      cst = sigmoidf_(gf) * cst + sigmoidf_(gi) * tanhf_(gg_);
      float hval = sigmoidf_(go) * tanhf_(cst);
      hbuf[(s + 1) & 1][q] = (signed char)(int)rintf(hval * 127.f);
      h_out[((size_t)chain * 512 + t) * 256 + q] = __float2bfloat16(hval);
    }
    __syncthreads();
  }

  // opaque guard: x values are in [0, V), so this never executes, but the
  // compiler cannot prove it -> force_lds stays allocated.
  if (tid == 0 && x[0] == -2147483647) {
    h_out[0] = __float2bfloat16((float)force_lds[chain]);
  }
}

// ---------------------------------------------------------------------------
// Kernel C: emissions GEMM. em[b*512+t][k] = Hcat[n]·w_out[k] + b_out[k]
// ---------------------------------------------------------------------------
__global__ __launch_bounds__(256) void emis_kernel(
    const __hip_bfloat16* __restrict__ h_glob, const float* __restrict__ w_out,
    const float* __restrict__ b_out, float* __restrict__ em) {
  __shared__ __align__(16) __hip_bfloat16 As[64][40];
  __shared__ __align__(16) __hip_bfloat16 Bs[32][40];
  const int tid = threadIdx.x;
  const int n0 = blockIdx.x * 64;
  const int lane = tid & 63, wave = tid >> 6, quad = lane >> 4, lm = lane & 15;
  float4v acc[2] = {};
  const int r = tid >> 2, c0 = (tid & 3) << 3;
  const int rb = tid >> 3, cb = (tid & 7) << 2;
  for (int ks = 0; ks < 16; ++ks) {
    const int j0 = ks * 32;
    const int dirk = j0 >> 8, jin = j0 & 255;
    const int n = n0 + r, bb = n >> 9, tt = n & 511;
    const uint4* src =
        (const uint4*)(h_glob + ((size_t)(dirk * 128 + bb) * 512 + tt) * 256 + jin + c0);
    *(uint4*)(&As[r][c0]) = *src;
#pragma unroll
    for (int e = 0; e < 4; ++e) {
      float v = (rb < 20) ? w_out[rb * 512 + j0 + cb + e] : 0.f;
      Bs[rb][cb + e] = __float2bfloat16(v);
    }
    __syncthreads();
    short8 af = *(const short8*)(&As[wave * 16 + lm][quad * 8]);
#pragma unroll
    for (int t2 = 0; t2 < 2; ++t2) {
      short8 bf = *(const short8*)(&Bs[t2 * 16 + lm][quad * 8]);
      acc[t2] = __builtin_amdgcn_mfma_f32_16x16x32_bf16(af, bf, acc[t2], 0, 0, 0);
    }
    __syncthreads();
  }
#pragma unroll
  for (int t2 = 0; t2 < 2; ++t2) {
#pragma unroll
    for (int rr = 0; rr < 4; ++rr) {
      int col = t2 * 16 + lm;
      if (col < 20) {
        int n = n0 + wave * 16 + quad * 4 + rr;
        em[(size_t)n * 20 + col] = acc[t2][rr] + b_out[col];
      }
    }
  }
}

// ---------------------------------------------------------------------------
// Kernel D: CRF forward NLL. 1 wave per batch element.
// ---------------------------------------------------------------------------
__global__ __launch_bounds__(64) void crf_kernel(
    const float* __restrict__ em, const int* __restrict__ y,
    const float* __restrict__ start_trans, const float* __restrict__ end_trans,
    const float* __restrict__ trans, float* __restrict__ partials) {
  const int b = blockIdx.x;
  const int lane = threadIdx.x;
  const int jj = lane < 20 ? lane : 19;
  const bool act = lane < 20;
  __shared__ float sea[2][64];
  const float* __restrict__ emb = em + (size_t)b * 512 * 20;
  const int* __restrict__ yb = y + b * 512;

  // ---- gold-path score, parallel over t ----
  float s_part = 0.f;
#pragma unroll
  for (int i = 0; i < 8; ++i) {
    int t = lane + 64 * i;
    int yc = yb[t];
    float v = emb[t * 20 + yc];
    v += (t == 0) ? start_trans[yc] : trans[yb[t - 1] * 20 + yc];
    s_part += v;
  }
#pragma unroll
  for (int k = 32; k >= 1; k >>= 1) s_part += __shfl_xor(s_part, k, 64);
  float score = s_part + end_trans[yb[511]];

  // ---- forward algorithm ----
  float ET[20];
#pragma unroll
  for (int i = 0; i < 20; ++i) ET[i] = __expf(trans[i * 20 + jj]);
  float alpha = act ? (start_trans[jj] + emb[jj]) : -1e30f;
  float P = alpha;
#pragma unroll
  for (int k = 32; k >= 1; k >>= 1) P = fmaxf(P, __shfl_xor(P, k, 64));

  float eC = emb[1 * 20 + jj];
  float eN = emb[2 * 20 + jj];
  for (int t = 1; t < 512; ++t) {
    if ((t & 15) == 0) {
      P = alpha;
#pragma unroll
      for (int k = 32; k >= 1; k >>= 1) P = fmaxf(P, __shfl_xor(P, k, 64));
    }
    sea[t & 1][lane] = __expf(alpha - P);
    int tf = t + 2 < 512 ? t + 2 : 511;
    float eF = emb[tf * 20 + jj];
    __syncthreads();
    float s0 = 0.f, s1 = 0.f;
#pragma unroll
    for (int i = 0; i < 20; i += 2) {
      s0 += sea[t & 1][i] * ET[i];
      s1 += sea[t & 1][i + 1] * ET[i + 1];
    }
    if (act) alpha = P + __logf(s0 + s1) + eC;
    eC = eN;
    eN = eF;
  }
  float v = act ? (alpha + end_trans[jj]) : -1e30f;
  float Pz = v;
#pragma unroll
  for (int k = 32; k >= 1; k >>= 1) Pz = fmaxf(Pz, __shfl_xor(Pz, k, 64));
  float e2 = __expf(v - Pz);
#pragma unroll
  for (int k = 32; k >= 1; k >>= 1) e2 += __shfl_xor(e2, k, 64);
  float logZ = Pz + __logf(e2);
  if (lane == 0) partials[b] = logZ - score;
}

__global__ __launch_bounds__(128) void reduce_kernel(const float* __restrict__ partials,
                                                     float* __restrict__ out) {
  const int tid = threadIdx.x;
  float v = partials[tid];
#pragma unroll
  for (int k = 32; k >= 1; k >>= 1) v += __shfl_xor(v, k, 64);
  __shared__ float tmp[2];
  if ((tid & 63) == 0) tmp[tid >> 6] = v;
  __syncthreads();
  if (tid == 0) out[0] = tmp[0] + tmp[1];
}

// ---------------------------------------------------------------------------
extern "C" void kernel_launch(void* const* d_in, const int* in_sizes, int n_in,
                              void* d_out, int out_size, void* d_ws, size_t ws_size,
                              hipStream_t stream) {
  const int* x = (const int*)d_in[0];
  const int* y = (const int*)d_in[1];
  const int* pre_tags = (const int*)d_in[2];
  const int* pinyin_tags = (const int*)d_in[3];
  const float* char_emb = (const float*)d_in[5];
  const float* tag_emb = (const float*)d_in[6];
  const float* pinyin_emb = (const float*)d_in[7];
  const float* w_ih_f = (const float*)d_in[8];
  const float* w_hh_f = (const float*)d_in[9];
  const float* b_ih_f = (const float*)d_in[10];
  const float* b_hh_f = (const float*)d_in[11];
  const float* w_ih_b = (const float*)d_in[12];
  const float* w_hh_b = (const float*)d_in[13];
  const float* b_ih_b = (const float*)d_in[14];
  const float* b_hh_b = (const float*)d_in[15];
  const float* w_out = (const float*)d_in[16];
  const float* b_out = (const float*)d_in[17];
  const float* start_trans = (const float*)d_in[18];
  const float* end_trans = (const float*)d_in[19];
  const float* trans = (const float*)d_in[20];

  char* ws = (char*)d_ws;
  __hip_bfloat16* char_proj = (__hip_bfloat16*)(ws);            // 10002*2048*2 = 40968192
  __hip_bfloat16* pin_proj = (__hip_bfloat16*)(ws + 40968192);  // 500*2048*2  = 2048000
  __hip_bfloat16* tag_proj = (__hip_bfloat16*)(ws + 43016192);  // 20*2048*2   = 81920
  __hip_bfloat16* h_glob = (__hip_bfloat16*)(ws + 43098112);    // 2*128*512*256*2 = 67108864
  float* em = (float*)(ws + 110206976);                         // 65536*20*4 = 5242880
  float* partials = (float*)(ws + 115449856);                   // 128*4

  proj_gemm<<<dim3(157, 8), 256, 0, stream>>>(char_emb, 10002, 300, 0, w_ih_f, w_ih_b,
                                              nullptr, nullptr, nullptr, nullptr, char_proj, 0);
  proj_gemm<<<dim3(8, 8), 256, 0, stream>>>(pinyin_emb, 500, 100, 300, w_ih_f, w_ih_b,
                                            nullptr, nullptr, nullptr, nullptr, pin_proj, 0);
  proj_gemm<<<dim3(1, 8), 256, 0, stream>>>(tag_emb, 20, 50, 400, w_ih_f, w_ih_b,
                                            b_ih_f, b_hh_f, b_ih_b, b_hh_b, tag_proj, 1);

  lstm_kernel<<<256, 1024, 0, stream>>>(w_hh_f, w_hh_b, x, pinyin_tags, pre_tags,
                                        (const char*)char_proj, (const char*)pin_proj,
                                        (const char*)tag_proj, h_glob);

  emis_kernel<<<1024, 256, 0, stream>>>(h_glob, w_out, b_out, em);
  crf_kernel<<<128, 64, 0, stream>>>(em, y, start_trans, end_trans, trans, partials);
  reduce_kernel<<<1, 128, 0, stream>>>(partials, (float*)d_out);
}

// Round 7
// 1189.909 us; speedup vs baseline: 1.4030x; 1.4030x over previous
//
#include <hip/hip_runtime.h>
#include <hip/hip_bf16.h>

typedef __attribute__((ext_vector_type(8))) short short8;
typedef __attribute__((ext_vector_type(4))) float float4v;

#if __has_builtin(__builtin_amdgcn_sdot4)
#define DOT4(a, b, c) __builtin_amdgcn_sdot4((int)(a), (int)(b), (c), false)
#else
__device__ __forceinline__ int dot4_(int a, int b, int c) {
  c += (int)(signed char)(a) * (int)(signed char)(b);
  c += (int)(signed char)(a >> 8) * (int)(signed char)(b >> 8);
  c += (int)(signed char)(a >> 16) * (int)(signed char)(b >> 16);
  c += (a >> 24) * (b >> 24);
  return c;
}
#define DOT4(a, b, c) dot4_((int)(a), (int)(b), (c))
#endif

__device__ __forceinline__ float sigmoidf_(float x) {
  return __fdividef(1.f, 1.f + __expf(-x));
}
__device__ __forceinline__ float tanhf_(float x) {
  float e = __expf(2.f * x);
  return 1.f - __fdividef(2.f, e + 1.f);
}
__device__ __forceinline__ float bflo(unsigned int v) {
  return __uint_as_float(v << 16);
}
__device__ __forceinline__ float bfhi(unsigned int v) {
  return __uint_as_float(v & 0xffff0000u);
}

// quad (4-lane) butterflies via DPP quad_perm (VALU, not DS pipe)
template <int CTRL>
__device__ __forceinline__ int qadd_i(int v) {
  return v + __builtin_amdgcn_update_dpp(0, v, CTRL, 0xF, 0xF, true);
}
template <int CTRL>
__device__ __forceinline__ float qmax_f(float v) {
  int r = __builtin_amdgcn_update_dpp(0, __float_as_int(v), CTRL, 0xF, 0xF, true);
  return fmaxf(v, __int_as_float(r));
}
#define XOR1 0xB1  // quad_perm [1,0,3,2]
#define XOR2 0x4E  // quad_perm [2,3,0,1]

__device__ __forceinline__ int dot16_(const unsigned int* w, uint4 H0, uint4 H1, uint4 H2,
                                      uint4 H3) {
  int a = 0;
  a = DOT4(w[0], H0.x, a);
  a = DOT4(w[1], H0.y, a);
  a = DOT4(w[2], H0.z, a);
  a = DOT4(w[3], H0.w, a);
  a = DOT4(w[4], H1.x, a);
  a = DOT4(w[5], H1.y, a);
  a = DOT4(w[6], H1.z, a);
  a = DOT4(w[7], H1.w, a);
  a = DOT4(w[8], H2.x, a);
  a = DOT4(w[9], H2.y, a);
  a = DOT4(w[10], H2.z, a);
  a = DOT4(w[11], H2.w, a);
  a = DOT4(w[12], H3.x, a);
  a = DOT4(w[13], H3.y, a);
  a = DOT4(w[14], H3.z, a);
  a = DOT4(w[15], H3.w, a);
  return a;
}

// ---------------------------------------------------------------------------
// Kernel A: projected embedding tables.
// Logical col n in [0,2048): dir=n>>10, r=n&1023, gate=r>>8, u=r&255.
// Stored at out[m*2048 + dir*1024 + u*4 + gate]  ([row][dir][unit][i,f,g,o]).
// ---------------------------------------------------------------------------
__global__ __launch_bounds__(256) void proj_gemm(
    const float* __restrict__ A, int rowsA, int Kdim, int col_off,
    const float* __restrict__ wf, const float* __restrict__ wb,
    const float* __restrict__ bf1, const float* __restrict__ bf2,
    const float* __restrict__ bb1, const float* __restrict__ bb2,
    __hip_bfloat16* __restrict__ out, int add_bias) {
  __shared__ __align__(16) __hip_bfloat16 As[64][40];
  __shared__ __align__(16) __hip_bfloat16 Bs[256][40];
  const int tid = threadIdx.x;
  const int m0 = blockIdx.x * 64, n0 = blockIdx.y * 256;
  const int lane = tid & 63, wave = tid >> 6;
  const int quad = lane >> 4, lm = lane & 15;
  float4v acc[16] = {};
  const int ksteps = (Kdim + 31) >> 5;
  const int r = tid >> 2, c0 = (tid & 3) << 3;
  const int rb = tid >> 4, cb = (tid & 15) * 2;  // coalesced B staging
  for (int ks = 0; ks < ksteps; ++ks) {
    const int k0 = ks << 5;
#pragma unroll
    for (int e = 0; e < 8; ++e) {
      int kk = k0 + c0 + e;
      float av = (m0 + r < rowsA && kk < Kdim) ? A[(m0 + r) * Kdim + kk] : 0.f;
      As[r][c0 + e] = __float2bfloat16(av);
    }
    // B tile 256x32: 16 lanes cover one row's 32-col slice (coalesced float2)
#pragma unroll
    for (int j = 0; j < 16; ++j) {
      int n = n0 + rb + 16 * j;
      const float* __restrict__ wrow =
          (n < 1024) ? (wf + n * 450 + col_off) : (wb + (n - 1024) * 450 + col_off);
      int kk = k0 + cb;
      float b0 = 0.f, b1 = 0.f;
      if (kk < Kdim) {  // Kdim even: pairs never straddle
        float2 v = *(const float2*)(wrow + kk);
        b0 = v.x;
        b1 = v.y;
      }
      Bs[rb + 16 * j][cb] = __float2bfloat16(b0);
      Bs[rb + 16 * j][cb + 1] = __float2bfloat16(b1);
    }
    __syncthreads();
    short8 af = *(const short8*)(&As[wave * 16 + lm][quad * 8]);
#pragma unroll
    for (int t = 0; t < 16; ++t) {
      short8 bf = *(const short8*)(&Bs[t * 16 + lm][quad * 8]);
      acc[t] = __builtin_amdgcn_mfma_f32_16x16x32_bf16(af, bf, acc[t], 0, 0, 0);
    }
    __syncthreads();
  }
#pragma unroll
  for (int t = 0; t < 16; ++t) {
#pragma unroll
    for (int rr = 0; rr < 4; ++rr) {
      int m = m0 + wave * 16 + quad * 4 + rr;
      int col = n0 + t * 16 + lm;
      if (m < rowsA) {
        float v = acc[t][rr];
        if (add_bias)
          v += (col < 1024) ? (bf1[col] + bf2[col]) : (bb1[col - 1024] + bb2[col - 1024]);
        int dir = col >> 10, r2 = col & 1023;
        int gate = r2 >> 8, u = r2 & 255;
        out[m * 2048 + dir * 1024 + u * 4 + gate] = __float2bfloat16(v);
      }
    }
  }
}

// ---------------------------------------------------------------------------
// Kernel B: BiLSTM recurrence, int8 dot4, 512 threads/chain.
// Empirical allocator law (R1-R6): VGPR budget = 2048 wave-regs / (2 x WG
// waves) -> 512-thr WG gets 128 regs (confirmed 3x). Design fits 128:
// quad q owns units 2q,2q+1 (8 gate rows); lane e in [0,4) holds K-slice
// [64e,64e+64). 5 rows int8 in VGPRs (80 regs) + 3 rows streamed from LDS
// (3 planes x 512 thr x 80 B, 8-lane bank-complete stride).
// Live ~126 <= 128 -> no spill by construction.
// ---------------------------------------------------------------------------
#define PLANE_DW (512 * 20)  // dwords per LDS weight plane (16 data + 4 pad)

__global__ __launch_bounds__(512) void lstm_kernel(
    const float* __restrict__ whh_f, const float* __restrict__ whh_b,
    const int* __restrict__ x, const int* __restrict__ ptags, const int* __restrict__ gtags,
    const char* __restrict__ char_proj, const char* __restrict__ pin_proj,
    const char* __restrict__ tag_proj, __hip_bfloat16* __restrict__ h_out) {
  extern __shared__ __align__(16) char smem[];
  unsigned int* wlds = (unsigned int*)smem;          // 3*PLANE_DW*4 = 122880 B
  int4* sidx = (int4*)(smem + 122880);               // 8192 B
  signed char* hb = (signed char*)(smem + 131072);   // 2*256 = 512 B

  const int tid = threadIdx.x;
  const int q = tid >> 2, e = tid & 3;
  const int chain = blockIdx.x;
  const int dir = chain >> 7;
  const int b = chain & 127;
  const float* __restrict__ whh = dir ? whh_b : whh_f;
  const int unitA = 2 * q, unitB = 2 * q + 1;

  // stage index byte-offsets (table row pitch = 2048 bf16 = 4096 B)
  sidx[tid] = make_int4(x[b * 512 + tid] * 4096, ptags[b * 512 + tid] * 4096,
                        gtags[b * 512 + tid] * 4096, 0);
  if (tid < 16) ((int4*)hb)[tid] = make_int4(0, 0, 0, 0);

  // ---- int8-quantize 8 gate rows (5 -> VGPR, 3 -> LDS) ----
  // rr: 0=A.i 1=A.f 2=A.g 3=B.i 4=B.f 5=A.o 6=B.g 7=B.o
  const int rgate[8] = {0, 1, 2, 0, 1, 3, 2, 3};
  unsigned int Wreg[5][16];
  float sc4[4];  // lane e&1==0: unit A {i,f,g,o}; e&1==1: unit B {i,f,g,o}
  const int slotA[8] = {0, 1, 2, -1, -1, 3, -1, -1};
  const int slotB[8] = {-1, -1, -1, 0, 1, -1, 2, 3};
#pragma unroll
  for (int rr = 0; rr < 8; ++rr) {
    const int unit = (rr == 0 || rr == 1 || rr == 2 || rr == 5) ? unitA : unitB;
    const float* __restrict__ wr = whh + (rgate[rr] * 256 + unit) * 256 + e * 64;
    float mx = 0.f;
#pragma unroll
    for (int k4 = 0; k4 < 16; ++k4) {
      float4 v = ((const float4*)wr)[k4];
      mx = fmaxf(mx, fmaxf(fmaxf(fabsf(v.x), fabsf(v.y)), fmaxf(fabsf(v.z), fabsf(v.w))));
    }
    mx = qmax_f<XOR1>(mx);
    mx = qmax_f<XOR2>(mx);  // full-row max across 4 K-slices
    float inv = (mx > 0.f) ? __fdividef(127.f, mx) : 0.f;
    float scv = (mx > 0.f) ? (mx / (127.f * 127.f)) : 0.f;
    int slot = (e & 1) ? slotB[rr] : slotA[rr];
    if (slot >= 0) sc4[slot] = scv;
    unsigned int tmp[16];
#pragma unroll
    for (int k4 = 0; k4 < 16; ++k4) {
      float4 v = ((const float4*)wr)[k4];
      int b0 = (int)rintf(v.x * inv), b1 = (int)rintf(v.y * inv);
      int b2 = (int)rintf(v.z * inv), b3 = (int)rintf(v.w * inv);
      tmp[k4] = (unsigned int)((b0 & 0xff) | ((b1 & 0xff) << 8) | ((b2 & 0xff) << 16) |
                               ((b3 & 0xff) << 24));
    }
    if (rr < 5) {
#pragma unroll
      for (int k4 = 0; k4 < 16; ++k4) Wreg[rr][k4] = tmp[k4];
    } else {
      uint4* dst = (uint4*)(wlds + (rr - 5) * PLANE_DW + tid * 20);
#pragma unroll
      for (int j = 0; j < 4; ++j) dst[j] = make_uint4(tmp[4 * j], tmp[4 * j + 1],
                                                      tmp[4 * j + 2], tmp[4 * j + 3]);
    }
  }
  __syncthreads();

  const int myunit = (e & 1) ? unitB : unitA;
  const int pre_off = dir * 2048 + myunit * 8;  // bytes within a table row
  const unsigned int* wl0 = wlds + tid * 20;    // plane offsets via pointer math
  float cst = 0.f;

  // prefetch step 0 pre-gates (lanes e<2)
  int t_cur = dir ? 511 : 0;
  uint2 pc = {}, pp = {}, pt = {};
  if (e < 2) {
    int4 ix = sidx[t_cur];
    pc = *(const uint2*)(char_proj + ix.x + pre_off);
    pp = *(const uint2*)(pin_proj + ix.y + pre_off);
    pt = *(const uint2*)(tag_proj + ix.z + pre_off);
  }

  for (int s = 0; s < 512; ++s) {
    const int t = t_cur;
    const uint2 cv = pc, pv = pp, gv = pt;
    const int tn = dir ? (t > 0 ? t - 1 : 0) : (t < 511 ? t + 1 : 511);
    t_cur = tn;

    // h slice (64 int8 = 4 x b128), buffer parity = s
    const uint4* hv = (const uint4*)(hb + (s & 1) * 256 + e * 64);
    uint4 H0 = hv[0], H1 = hv[1], H2 = hv[2], H3 = hv[3];

    // prefetch next step's pre-gates
    if (e < 2) {
      int4 ix = sidx[tn];
      pc = *(const uint2*)(char_proj + ix.x + pre_off);
      pp = *(const uint2*)(pin_proj + ix.y + pre_off);
      pt = *(const uint2*)(tag_proj + ix.z + pre_off);
    }

    int acc[8];
#pragma unroll
    for (int rr = 0; rr < 5; ++rr) acc[rr] = dot16_(Wreg[rr], H0, H1, H2, H3);
#pragma unroll
    for (int lr = 0; lr < 3; ++lr) {
      unsigned int lw[16];
      const uint4* src = (const uint4*)(wl0 + lr * PLANE_DW);
#pragma unroll
      for (int j = 0; j < 4; ++j) {
        uint4 v = src[j];
        lw[4 * j] = v.x;
        lw[4 * j + 1] = v.y;
        lw[4 * j + 2] = v.z;
        lw[4 * j + 3] = v.w;
      }
      acc[5 + lr] = dot16_(lw, H0, H1, H2, H3);
    }
    // quad butterfly: all 4 lanes get full-K sums for all 8 rows
#pragma unroll
    for (int rr = 0; rr < 8; ++rr) {
      int v = qadd_i<XOR1>(acc[rr]);
      acc[rr] = qadd_i<XOR2>(v);
    }

    if (e < 2) {
      // lane e==0 -> unit A rows {0,1,2,5}; lane e==1 -> unit B rows {3,4,6,7}
      int ai = e ? acc[3] : acc[0];
      int af = e ? acc[4] : acc[1];
      int ag = e ? acc[6] : acc[2];
      int ao = e ? acc[7] : acc[5];
      // pre-gates: (i,f) in .x, (g,o) in .y of each table's uint2
      float gi = bflo(cv.x) + bflo(pv.x) + bflo(gv.x) + (float)ai * sc4[0];
      float gf = bfhi(cv.x) + bfhi(pv.x) + bfhi(gv.x) + (float)af * sc4[1];
      float gg = bflo(cv.y) + bflo(pv.y) + bflo(gv.y) + (float)ag * sc4[2];
      float go = bfhi(cv.y) + bfhi(pv.y) + bfhi(gv.y) + (float)ao * sc4[3];
      cst = sigmoidf_(gf) * cst + sigmoidf_(gi) * tanhf_(gg);
      float hval = sigmoidf_(go) * tanhf_(cst);
      hb[((s + 1) & 1) * 256 + myunit] = (signed char)(int)rintf(hval * 127.f);
      h_out[((size_t)chain * 512 + t) * 256 + myunit] = __float2bfloat16(hval);
    }
    __syncthreads();
  }
}

// ---------------------------------------------------------------------------
// Kernel C: emissions GEMM. em[b*512+t][k] = Hcat[n]·w_out[k] + b_out[k]
// ---------------------------------------------------------------------------
__global__ __launch_bounds__(256) void emis_kernel(
    const __hip_bfloat16* __restrict__ h_glob, const float* __restrict__ w_out,
    const float* __restrict__ b_out, float* __restrict__ em) {
  __shared__ __align__(16) __hip_bfloat16 As[64][40];
  __shared__ __align__(16) __hip_bfloat16 Bs[32][40];
  const int tid = threadIdx.x;
  const int n0 = blockIdx.x * 64;
  const int lane = tid & 63, wave = tid >> 6, quad = lane >> 4, lm = lane & 15;
  float4v acc[2] = {};
  const int r = tid >> 2, c0 = (tid & 3) << 3;
  const int rb = tid >> 3, cb = (tid & 7) << 2;
  for (int ks = 0; ks < 16; ++ks) {
    const int j0 = ks * 32;
    const int dirk = j0 >> 8, jin = j0 & 255;
    const int n = n0 + r, bb = n >> 9, tt = n & 511;
    const uint4* src =
        (const uint4*)(h_glob + ((size_t)(dirk * 128 + bb) * 512 + tt) * 256 + jin + c0);
    *(uint4*)(&As[r][c0]) = *src;
#pragma unroll
    for (int e = 0; e < 4; ++e) {
      float v = (rb < 20) ? w_out[rb * 512 + j0 + cb + e] : 0.f;
      Bs[rb][cb + e] = __float2bfloat16(v);
    }
    __syncthreads();
    short8 af = *(const short8*)(&As[wave * 16 + lm][quad * 8]);
#pragma unroll
    for (int t2 = 0; t2 < 2; ++t2) {
      short8 bf = *(const short8*)(&Bs[t2 * 16 + lm][quad * 8]);
      acc[t2] = __builtin_amdgcn_mfma_f32_16x16x32_bf16(af, bf, acc[t2], 0, 0, 0);
    }
    __syncthreads();
  }
#pragma unroll
  for (int t2 = 0; t2 < 2; ++t2) {
#pragma unroll
    for (int rr = 0; rr < 4; ++rr) {
      int col = t2 * 16 + lm;
      if (col < 20) {
        int n = n0 + wave * 16 + quad * 4 + rr;
        em[(size_t)n * 20 + col] = acc[t2][rr] + b_out[col];
      }
    }
  }
}

// ---------------------------------------------------------------------------
// Kernel D: CRF forward NLL. 1 wave per batch element.
// ---------------------------------------------------------------------------
__global__ __launch_bounds__(64) void crf_kernel(
    const float* __restrict__ em, const int* __restrict__ y,
    const float* __restrict__ start_trans, const float* __restrict__ end_trans,
    const float* __restrict__ trans, float* __restrict__ partials) {
  const int b = blockIdx.x;
  const int lane = threadIdx.x;
  const int jj = lane < 20 ? lane : 19;
  const bool act = lane < 20;
  __shared__ float sea[2][64];
  const float* __restrict__ emb = em + (size_t)b * 512 * 20;
  const int* __restrict__ yb = y + b * 512;

  // ---- gold-path score, parallel over t ----
  float s_part = 0.f;
#pragma unroll
  for (int i = 0; i < 8; ++i) {
    int t = lane + 64 * i;
    int yc = yb[t];
    float v = emb[t * 20 + yc];
    v += (t == 0) ? start_trans[yc] : trans[yb[t - 1] * 20 + yc];
    s_part += v;
  }
#pragma unroll
  for (int k = 32; k >= 1; k >>= 1) s_part += __shfl_xor(s_part, k, 64);
  float score = s_part + end_trans[yb[511]];

  // ---- forward algorithm ----
  float ET[20];
#pragma unroll
  for (int i = 0; i < 20; ++i) ET[i] = __expf(trans[i * 20 + jj]);
  float alpha = act ? (start_trans[jj] + emb[jj]) : -1e30f;
  float P = alpha;
#pragma unroll
  for (int k = 32; k >= 1; k >>= 1) P = fmaxf(P, __shfl_xor(P, k, 64));

  float eC = emb[1 * 20 + jj];
  float eN = emb[2 * 20 + jj];
  for (int t = 1; t < 512; ++t) {
    if ((t & 15) == 0) {
      P = alpha;
#pragma unroll
      for (int k = 32; k >= 1; k >>= 1) P = fmaxf(P, __shfl_xor(P, k, 64));
    }
    sea[t & 1][lane] = __expf(alpha - P);
    int tf = t + 2 < 512 ? t + 2 : 511;
    float eF = emb[tf * 20 + jj];
    __syncthreads();
    float s0 = 0.f, s1 = 0.f;
#pragma unroll
    for (int i = 0; i < 20; i += 2) {
      s0 += sea[t & 1][i] * ET[i];
      s1 += sea[t & 1][i + 1] * ET[i + 1];
    }
    if (act) alpha = P + __logf(s0 + s1) + eC;
    eC = eN;
    eN = eF;
  }
  float v = act ? (alpha + end_trans[jj]) : -1e30f;
  float Pz = v;
#pragma unroll
  for (int k = 32; k >= 1; k >>= 1) Pz = fmaxf(Pz, __shfl_xor(Pz, k, 64));
  float e2 = __expf(v - Pz);
#pragma unroll
  for (int k = 32; k >= 1; k >>= 1) e2 += __shfl_xor(e2, k, 64);
  float logZ = Pz + __logf(e2);
  if (lane == 0) partials[b] = logZ - score;
}

__global__ __launch_bounds__(128) void reduce_kernel(const float* __restrict__ partials,
                                                     float* __restrict__ out) {
  const int tid = threadIdx.x;
  float v = partials[tid];
#pragma unroll
  for (int k = 32; k >= 1; k >>= 1) v += __shfl_xor(v, k, 64);
  __shared__ float tmp[2];
  if ((tid & 63) == 0) tmp[tid >> 6] = v;
  __syncthreads();
  if (tid == 0) out[0] = tmp[0] + tmp[1];
}

// ---------------------------------------------------------------------------
extern "C" void kernel_launch(void* const* d_in, const int* in_sizes, int n_in,
                              void* d_out, int out_size, void* d_ws, size_t ws_size,
                              hipStream_t stream) {
  const int* x = (const int*)d_in[0];
  const int* y = (const int*)d_in[1];
  const int* pre_tags = (const int*)d_in[2];
  const int* pinyin_tags = (const int*)d_in[3];
  const float* char_emb = (const float*)d_in[5];
  const float* tag_emb = (const float*)d_in[6];
  const float* pinyin_emb = (const float*)d_in[7];
  const float* w_ih_f = (const float*)d_in[8];
  const float* w_hh_f = (const float*)d_in[9];
  const float* b_ih_f = (const float*)d_in[10];
  const float* b_hh_f = (const float*)d_in[11];
  const float* w_ih_b = (const float*)d_in[12];
  const float* w_hh_b = (const float*)d_in[13];
  const float* b_ih_b = (const float*)d_in[14];
  const float* b_hh_b = (const float*)d_in[15];
  const float* w_out = (const float*)d_in[16];
  const float* b_out = (const float*)d_in[17];
  const float* start_trans = (const float*)d_in[18];
  const float* end_trans = (const float*)d_in[19];
  const float* trans = (const float*)d_in[20];

  char* ws = (char*)d_ws;
  __hip_bfloat16* char_proj = (__hip_bfloat16*)(ws);            // 10002*2048*2 = 40968192
  __hip_bfloat16* pin_proj = (__hip_bfloat16*)(ws + 40968192);  // 500*2048*2  = 2048000
  __hip_bfloat16* tag_proj = (__hip_bfloat16*)(ws + 43016192);  // 20*2048*2   = 81920
  __hip_bfloat16* h_glob = (__hip_bfloat16*)(ws + 43098112);    // 2*128*512*256*2 = 67108864
  float* em = (float*)(ws + 110206976);                         // 65536*20*4 = 5242880
  float* partials = (float*)(ws + 115449856);                   // 128*4

  proj_gemm<<<dim3(157, 8), 256, 0, stream>>>(char_emb, 10002, 300, 0, w_ih_f, w_ih_b,
                                              nullptr, nullptr, nullptr, nullptr, char_proj, 0);
  proj_gemm<<<dim3(8, 8), 256, 0, stream>>>(pinyin_emb, 500, 100, 300, w_ih_f, w_ih_b,
                                            nullptr, nullptr, nullptr, nullptr, pin_proj, 0);
  proj_gemm<<<dim3(1, 8), 256, 0, stream>>>(tag_emb, 20, 50, 400, w_ih_f, w_ih_b,
                                            b_ih_f, b_hh_f, b_ih_b, b_hh_b, tag_proj, 1);

  const int lstm_lds = 131584;  // 122880 wlds + 8192 sidx + 512 hbuf
  hipFuncSetAttribute((const void*)lstm_kernel, hipFuncAttributeMaxDynamicSharedMemorySize,
                      lstm_lds);
  lstm_kernel<<<256, 512, lstm_lds, stream>>>(w_hh_f, w_hh_b, x, pinyin_tags, pre_tags,
                                              (const char*)char_proj, (const char*)pin_proj,
                                              (const char*)tag_proj, h_glob);

  emis_kernel<<<1024, 256, 0, stream>>>(h_glob, w_out, b_out, em);
  crf_kernel<<<128, 64, 0, stream>>>(em, y, start_trans, end_trans, trans, partials);
  reduce_kernel<<<1, 128, 0, stream>>>(partials, (float*)d_out);
}

// Round 8
// 1130.827 us; speedup vs baseline: 1.4763x; 1.0522x over previous
//
#include <hip/hip_runtime.h>
#include <hip/hip_bf16.h>

typedef __attribute__((ext_vector_type(8))) short short8;
typedef __attribute__((ext_vector_type(4))) float float4v;

#if __has_builtin(__builtin_amdgcn_sdot4)
#define DOT4(a, b, c) __builtin_amdgcn_sdot4((int)(a), (int)(b), (c), false)
#else
__device__ __forceinline__ int dot4_(int a, int b, int c) {
  c += (int)(signed char)(a) * (int)(signed char)(b);
  c += (int)(signed char)(a >> 8) * (int)(signed char)(b >> 8);
  c += (int)(signed char)(a >> 16) * (int)(signed char)(b >> 16);
  c += (a >> 24) * (b >> 24);
  return c;
}
#define DOT4(a, b, c) dot4_((int)(a), (int)(b), (c))
#endif

__device__ __forceinline__ float sigmoidf_(float x) {
  return __fdividef(1.f, 1.f + __expf(-x));
}
__device__ __forceinline__ float tanhf_(float x) {
  float e = __expf(2.f * x);
  return 1.f - __fdividef(2.f, e + 1.f);
}
__device__ __forceinline__ float bflo(unsigned int v) {
  return __uint_as_float(v << 16);
}
__device__ __forceinline__ float bfhi(unsigned int v) {
  return __uint_as_float(v & 0xffff0000u);
}

// quad (4-lane) butterflies via DPP quad_perm (VALU, not DS pipe)
template <int CTRL>
__device__ __forceinline__ int qadd_i(int v) {
  return v + __builtin_amdgcn_update_dpp(0, v, CTRL, 0xF, 0xF, true);
}
template <int CTRL>
__device__ __forceinline__ float qmax_f(float v) {
  int r = __builtin_amdgcn_update_dpp(0, __float_as_int(v), CTRL, 0xF, 0xF, true);
  return fmaxf(v, __int_as_float(r));
}
#define XOR1 0xB1  // quad_perm [1,0,3,2]
#define XOR2 0x4E  // quad_perm [2,3,0,1]

__device__ __forceinline__ unsigned int pack4_(float4 v, float inv) {
  int b0 = (int)rintf(v.x * inv), b1 = (int)rintf(v.y * inv);
  int b2 = (int)rintf(v.z * inv), b3 = (int)rintf(v.w * inv);
  return (unsigned int)((b0 & 0xff) | ((b1 & 0xff) << 8) | ((b2 & 0xff) << 16) |
                        ((b3 & 0xff) << 24));
}

// ---------------------------------------------------------------------------
// Kernel A: projected embedding tables.
// Logical col n in [0,2048): dir=n>>10, r=n&1023, gate=r>>8, u=r&255.
// Stored at out[m*2048 + dir*1024 + u*4 + gate]  ([row][dir][unit][i,f,g,o]).
// ---------------------------------------------------------------------------
__global__ __launch_bounds__(256) void proj_gemm(
    const float* __restrict__ A, int rowsA, int Kdim, int col_off,
    const float* __restrict__ wf, const float* __restrict__ wb,
    const float* __restrict__ bf1, const float* __restrict__ bf2,
    const float* __restrict__ bb1, const float* __restrict__ bb2,
    __hip_bfloat16* __restrict__ out, int add_bias) {
  __shared__ __align__(16) __hip_bfloat16 As[64][40];
  __shared__ __align__(16) __hip_bfloat16 Bs[256][40];
  const int tid = threadIdx.x;
  const int m0 = blockIdx.x * 64, n0 = blockIdx.y * 256;
  const int lane = tid & 63, wave = tid >> 6;
  const int quad = lane >> 4, lm = lane & 15;
  float4v acc[16] = {};
  const int ksteps = (Kdim + 31) >> 5;
  const int r = tid >> 2, c0 = (tid & 3) << 3;
  const int rb = tid >> 4, cb = (tid & 15) * 2;  // coalesced B staging
  for (int ks = 0; ks < ksteps; ++ks) {
    const int k0 = ks << 5;
#pragma unroll
    for (int e = 0; e < 8; ++e) {
      int kk = k0 + c0 + e;
      float av = (m0 + r < rowsA && kk < Kdim) ? A[(m0 + r) * Kdim + kk] : 0.f;
      As[r][c0 + e] = __float2bfloat16(av);
    }
#pragma unroll
    for (int j = 0; j < 16; ++j) {
      int n = n0 + rb + 16 * j;
      const float* __restrict__ wrow =
          (n < 1024) ? (wf + n * 450 + col_off) : (wb + (n - 1024) * 450 + col_off);
      int kk = k0 + cb;
      float b0 = 0.f, b1 = 0.f;
      if (kk < Kdim) {
        float2 v = *(const float2*)(wrow + kk);
        b0 = v.x;
        b1 = v.y;
      }
      Bs[rb + 16 * j][cb] = __float2bfloat16(b0);
      Bs[rb + 16 * j][cb + 1] = __float2bfloat16(b1);
    }
    __syncthreads();
    short8 af = *(const short8*)(&As[wave * 16 + lm][quad * 8]);
#pragma unroll
    for (int t = 0; t < 16; ++t) {
      short8 bf = *(const short8*)(&Bs[t * 16 + lm][quad * 8]);
      acc[t] = __builtin_amdgcn_mfma_f32_16x16x32_bf16(af, bf, acc[t], 0, 0, 0);
    }
    __syncthreads();
  }
#pragma unroll
  for (int t = 0; t < 16; ++t) {
#pragma unroll
    for (int rr = 0; rr < 4; ++rr) {
      int m = m0 + wave * 16 + quad * 4 + rr;
      int col = n0 + t * 16 + lm;
      if (m < rowsA) {
        float v = acc[t][rr];
        if (add_bias)
          v += (col < 1024) ? (bf1[col] + bf2[col]) : (bb1[col - 1024] + bb2[col - 1024]);
        int dir = col >> 10, r2 = col & 1023;
        int gate = r2 >> 8, u = r2 & 255;
        out[m * 2048 + dir * 1024 + u * 4 + gate] = __float2bfloat16(v);
      }
    }
  }
}

// ---------------------------------------------------------------------------
// Kernel B: BiLSTM recurrence, int8 dot4, 256 threads/chain (4 waves).
// Allocator law (6 data pts, R1-R7): VGPR budget = 2048/(2 x WG waves).
// 4-wave WG -> 256 VGPRs. Quad q owns units 4q..4q+3 (16 gate rows); lane
// e holds K-slice [64e,64e+64). 12 rows int8 in VGPRs (192 regs), 4 rows
// (unit 4q+3's i,f,g,o) in LDS planes. Plane slot rotated by (tid>>3)&3 so
// bank-colliding lanes (L, L+8 at 80 B stride) read different banks.
// Live ~247 <= 256 -> no spill by construction.
// ---------------------------------------------------------------------------
#define PLANE_DW2 (256 * 20)  // dwords per LDS weight plane (16 data + 4 pad)

__global__ __launch_bounds__(256) void lstm_kernel(
    const float* __restrict__ whh_f, const float* __restrict__ whh_b,
    const int* __restrict__ x, const int* __restrict__ ptags, const int* __restrict__ gtags,
    const char* __restrict__ char_proj, const char* __restrict__ pin_proj,
    const char* __restrict__ tag_proj, __hip_bfloat16* __restrict__ h_out) {
  extern __shared__ __align__(16) char smem[];
  unsigned int* wlds = (unsigned int*)smem;        // 4*PLANE_DW2*4 = 81920 B
  int4* sidx = (int4*)(smem + 81920);              // 8192 B
  signed char* hb = (signed char*)(smem + 90112);  // 2*256 = 512 B

  const int tid = threadIdx.x;
  const int q = tid >> 2, e = tid & 3;
  const int chain = blockIdx.x;
  const int dir = chain >> 7;
  const int b = chain & 127;
  const float* __restrict__ whh = dir ? whh_b : whh_f;
  const int rot = (tid >> 3) & 3;

  // stage index byte-offsets (table row pitch = 2048 bf16 = 4096 B)
  sidx[tid] = make_int4(x[b * 512 + tid] * 4096, ptags[b * 512 + tid] * 4096,
                        gtags[b * 512 + tid] * 4096, 0);
  sidx[tid + 256] = make_int4(x[b * 512 + tid + 256] * 4096, ptags[b * 512 + tid + 256] * 4096,
                              gtags[b * 512 + tid + 256] * 4096, 0);
  if (tid < 32) ((int4*)hb)[tid] = make_int4(0, 0, 0, 0);

  // ---- int8-quantize 16 gate rows (12 -> VGPR, 4 -> LDS planes) ----
  unsigned int Wreg[12][16];
  float sc4[4];
#pragma unroll
  for (int rr = 0; rr < 16; ++rr) {
    const int unit = 4 * q + (rr >> 2), gate = rr & 3;
    const float* __restrict__ wr = whh + (gate * 256 + unit) * 256 + e * 64;
    float mx = 0.f;
#pragma unroll
    for (int k4 = 0; k4 < 16; ++k4) {
      float4 v = ((const float4*)wr)[k4];
      mx = fmaxf(mx, fmaxf(fmaxf(fabsf(v.x), fabsf(v.y)), fmaxf(fabsf(v.z), fabsf(v.w))));
    }
    mx = qmax_f<XOR1>(mx);
    mx = qmax_f<XOR2>(mx);  // full-row max across the quad's 4 K-slices
    float inv = (mx > 0.f) ? __fdividef(127.f, mx) : 0.f;
    float scv = (mx > 0.f) ? (mx / (127.f * 127.f)) : 0.f;
    if ((rr >> 2) == e) sc4[gate] = scv;  // lane keeps scales of ITS unit
    if (rr < 12) {
#pragma unroll
      for (int k4 = 0; k4 < 16; ++k4) Wreg[rr][k4] = pack4_(((const float4*)wr)[k4], inv);
    } else {
      const int p = rr - 12;
#pragma unroll
      for (int c = 0; c < 4; ++c) {
        uint4 tv;
        tv.x = pack4_(((const float4*)wr)[c * 4 + 0], inv);
        tv.y = pack4_(((const float4*)wr)[c * 4 + 1], inv);
        tv.z = pack4_(((const float4*)wr)[c * 4 + 2], inv);
        tv.w = pack4_(((const float4*)wr)[c * 4 + 3], inv);
        int slot = (c + rot) & 3;
        *(uint4*)(wlds + p * PLANE_DW2 + tid * 20 + slot * 4) = tv;
      }
    }
  }
  __syncthreads();

  const int myu = 4 * q + e;
  const int pre_off = dir * 2048 + myu * 8;  // bytes within a table row
  float cst = 0.f;
  const unsigned int* pb0 = wlds + 0 * PLANE_DW2 + tid * 20;
  const unsigned int* pb1 = wlds + 1 * PLANE_DW2 + tid * 20;
  const unsigned int* pb2 = wlds + 2 * PLANE_DW2 + tid * 20;
  const unsigned int* pb3 = wlds + 3 * PLANE_DW2 + tid * 20;
  int sl[4];
#pragma unroll
  for (int c = 0; c < 4; ++c) sl[c] = ((c + rot) & 3) * 4;

  // prefetch step 0 pre-gates (all lanes: each owns one unit)
  int t_cur = dir ? 511 : 0;
  uint2 pc, pp, pt;
  {
    int4 ix = sidx[t_cur];
    pc = *(const uint2*)(char_proj + ix.x + pre_off);
    pp = *(const uint2*)(pin_proj + ix.y + pre_off);
    pt = *(const uint2*)(tag_proj + ix.z + pre_off);
  }

  for (int s = 0; s < 512; ++s) {
    const int t = t_cur;
    const uint2 cv = pc, pv = pp, gv = pt;
    const int tn = dir ? (t > 0 ? t - 1 : 0) : (t < 511 ? t + 1 : 511);
    t_cur = tn;
    {
      int4 ix = sidx[tn];
      pc = *(const uint2*)(char_proj + ix.x + pre_off);
      pp = *(const uint2*)(pin_proj + ix.y + pre_off);
      pt = *(const uint2*)(tag_proj + ix.z + pre_off);
    }

    const signed char* hbase = hb + (s & 1) * 256 + e * 64;
    int acc[16] = {0, 0, 0, 0, 0, 0, 0, 0, 0, 0, 0, 0, 0, 0, 0, 0};
#pragma unroll
    for (int c = 0; c < 4; ++c) {
      uint4 H = *(const uint4*)(hbase + c * 16);
#pragma unroll
      for (int rr = 0; rr < 12; ++rr) {
        acc[rr] = DOT4(Wreg[rr][4 * c + 0], H.x, acc[rr]);
        acc[rr] = DOT4(Wreg[rr][4 * c + 1], H.y, acc[rr]);
        acc[rr] = DOT4(Wreg[rr][4 * c + 2], H.z, acc[rr]);
        acc[rr] = DOT4(Wreg[rr][4 * c + 3], H.w, acc[rr]);
      }
      {
        uint4 wv = *(const uint4*)(pb0 + sl[c]);
        acc[12] = DOT4(wv.x, H.x, acc[12]);
        acc[12] = DOT4(wv.y, H.y, acc[12]);
        acc[12] = DOT4(wv.z, H.z, acc[12]);
        acc[12] = DOT4(wv.w, H.w, acc[12]);
      }
      {
        uint4 wv = *(const uint4*)(pb1 + sl[c]);
        acc[13] = DOT4(wv.x, H.x, acc[13]);
        acc[13] = DOT4(wv.y, H.y, acc[13]);
        acc[13] = DOT4(wv.z, H.z, acc[13]);
        acc[13] = DOT4(wv.w, H.w, acc[13]);
      }
      {
        uint4 wv = *(const uint4*)(pb2 + sl[c]);
        acc[14] = DOT4(wv.x, H.x, acc[14]);
        acc[14] = DOT4(wv.y, H.y, acc[14]);
        acc[14] = DOT4(wv.z, H.z, acc[14]);
        acc[14] = DOT4(wv.w, H.w, acc[14]);
      }
      {
        uint4 wv = *(const uint4*)(pb3 + sl[c]);
        acc[15] = DOT4(wv.x, H.x, acc[15]);
        acc[15] = DOT4(wv.y, H.y, acc[15]);
        acc[15] = DOT4(wv.z, H.z, acc[15]);
        acc[15] = DOT4(wv.w, H.w, acc[15]);
      }
    }
    // quad butterfly: all 4 lanes get full-K sums for all 16 rows
#pragma unroll
    for (int rr = 0; rr < 16; ++rr) {
      int v = qadd_i<XOR1>(acc[rr]);
      acc[rr] = qadd_i<XOR2>(v);
    }
    // lane e picks its unit's rows (constant-index cndmask chains)
    int ai = e == 0 ? acc[0] : (e == 1 ? acc[4] : (e == 2 ? acc[8] : acc[12]));
    int af = e == 0 ? acc[1] : (e == 1 ? acc[5] : (e == 2 ? acc[9] : acc[13]));
    int ag = e == 0 ? acc[2] : (e == 1 ? acc[6] : (e == 2 ? acc[10] : acc[14]));
    int ao = e == 0 ? acc[3] : (e == 1 ? acc[7] : (e == 2 ? acc[11] : acc[15]));
    // pre-gates: (i,f) in .x, (g,o) in .y of each table's uint2
    float gi = bflo(cv.x) + bflo(pv.x) + bflo(gv.x) + (float)ai * sc4[0];
    float gf = bfhi(cv.x) + bfhi(pv.x) + bfhi(gv.x) + (float)af * sc4[1];
    float gg = bflo(cv.y) + bflo(pv.y) + bflo(gv.y) + (float)ag * sc4[2];
    float go = bfhi(cv.y) + bfhi(pv.y) + bfhi(gv.y) + (float)ao * sc4[3];
    cst = sigmoidf_(gf) * cst + sigmoidf_(gi) * tanhf_(gg);
    float hval = sigmoidf_(go) * tanhf_(cst);
    hb[((s + 1) & 1) * 256 + myu] = (signed char)(int)rintf(hval * 127.f);
    h_out[((size_t)chain * 512 + t) * 256 + myu] = __float2bfloat16(hval);
    __syncthreads();
  }
}

// ---------------------------------------------------------------------------
// Kernel C: emissions GEMM. em[b*512+t][k] = Hcat[n]·w_out[k] + b_out[k]
// ---------------------------------------------------------------------------
__global__ __launch_bounds__(256) void emis_kernel(
    const __hip_bfloat16* __restrict__ h_glob, const float* __restrict__ w_out,
    const float* __restrict__ b_out, float* __restrict__ em) {
  __shared__ __align__(16) __hip_bfloat16 As[64][40];
  __shared__ __align__(16) __hip_bfloat16 Bs[32][40];
  const int tid = threadIdx.x;
  const int n0 = blockIdx.x * 64;
  const int lane = tid & 63, wave = tid >> 6, quad = lane >> 4, lm = lane & 15;
  float4v acc[2] = {};
  const int r = tid >> 2, c0 = (tid & 3) << 3;
  const int rb = tid >> 3, cb = (tid & 7) << 2;
  for (int ks = 0; ks < 16; ++ks) {
    const int j0 = ks * 32;
    const int dirk = j0 >> 8, jin = j0 & 255;
    const int n = n0 + r, bb = n >> 9, tt = n & 511;
    const uint4* src =
        (const uint4*)(h_glob + ((size_t)(dirk * 128 + bb) * 512 + tt) * 256 + jin + c0);
    *(uint4*)(&As[r][c0]) = *src;
#pragma unroll
    for (int e = 0; e < 4; ++e) {
      float v = (rb < 20) ? w_out[rb * 512 + j0 + cb + e] : 0.f;
      Bs[rb][cb + e] = __float2bfloat16(v);
    }
    __syncthreads();
    short8 af = *(const short8*)(&As[wave * 16 + lm][quad * 8]);
#pragma unroll
    for (int t2 = 0; t2 < 2; ++t2) {
      short8 bf = *(const short8*)(&Bs[t2 * 16 + lm][quad * 8]);
      acc[t2] = __builtin_amdgcn_mfma_f32_16x16x32_bf16(af, bf, acc[t2], 0, 0, 0);
    }
    __syncthreads();
  }
#pragma unroll
  for (int t2 = 0; t2 < 2; ++t2) {
#pragma unroll
    for (int rr = 0; rr < 4; ++rr) {
      int col = t2 * 16 + lm;
      if (col < 20) {
        int n = n0 + wave * 16 + quad * 4 + rr;
        em[(size_t)n * 20 + col] = acc[t2][rr] + b_out[col];
      }
    }
  }
}

// ---------------------------------------------------------------------------
// Kernel D: CRF forward NLL. 1 wave per batch element.
// ---------------------------------------------------------------------------
__global__ __launch_bounds__(64) void crf_kernel(
    const float* __restrict__ em, const int* __restrict__ y,
    const float* __restrict__ start_trans, const float* __restrict__ end_trans,
    const float* __restrict__ trans, float* __restrict__ partials) {
  const int b = blockIdx.x;
  const int lane = threadIdx.x;
  const int jj = lane < 20 ? lane : 19;
  const bool act = lane < 20;
  __shared__ float sea[2][64];
  const float* __restrict__ emb = em + (size_t)b * 512 * 20;
  const int* __restrict__ yb = y + b * 512;

  float s_part = 0.f;
#pragma unroll
  for (int i = 0; i < 8; ++i) {
    int t = lane + 64 * i;
    int yc = yb[t];
    float v = emb[t * 20 + yc];
    v += (t == 0) ? start_trans[yc] : trans[yb[t - 1] * 20 + yc];
    s_part += v;
  }
#pragma unroll
  for (int k = 32; k >= 1; k >>= 1) s_part += __shfl_xor(s_part, k, 64);
  float score = s_part + end_trans[yb[511]];

  float ET[20];
#pragma unroll
  for (int i = 0; i < 20; ++i) ET[i] = __expf(trans[i * 20 + jj]);
  float alpha = act ? (start_trans[jj] + emb[jj]) : -1e30f;
  float P = alpha;
#pragma unroll
  for (int k = 32; k >= 1; k >>= 1) P = fmaxf(P, __shfl_xor(P, k, 64));

  float eC = emb[1 * 20 + jj];
  float eN = emb[2 * 20 + jj];
  for (int t = 1; t < 512; ++t) {
    if ((t & 15) == 0) {
      P = alpha;
#pragma unroll
      for (int k = 32; k >= 1; k >>= 1) P = fmaxf(P, __shfl_xor(P, k, 64));
    }
    sea[t & 1][lane] = __expf(alpha - P);
    int tf = t + 2 < 512 ? t + 2 : 511;
    float eF = emb[tf * 20 + jj];
    __syncthreads();
    float s0 = 0.f, s1 = 0.f;
#pragma unroll
    for (int i = 0; i < 20; i += 2) {
      s0 += sea[t & 1][i] * ET[i];
      s1 += sea[t & 1][i + 1] * ET[i + 1];
    }
    if (act) alpha = P + __logf(s0 + s1) + eC;
    eC = eN;
    eN = eF;
  }
  float v = act ? (alpha + end_trans[jj]) : -1e30f;
  float Pz = v;
#pragma unroll
  for (int k = 32; k >= 1; k >>= 1) Pz = fmaxf(Pz, __shfl_xor(Pz, k, 64));
  float e2 = __expf(v - Pz);
#pragma unroll
  for (int k = 32; k >= 1; k >>= 1) e2 += __shfl_xor(e2, k, 64);
  float logZ = Pz + __logf(e2);
  if (lane == 0) partials[b] = logZ - score;
}

__global__ __launch_bounds__(128) void reduce_kernel(const float* __restrict__ partials,
                                                     float* __restrict__ out) {
  const int tid = threadIdx.x;
  float v = partials[tid];
#pragma unroll
  for (int k = 32; k >= 1; k >>= 1) v += __shfl_xor(v, k, 64);
  __shared__ float tmp[2];
  if ((tid & 63) == 0) tmp[tid >> 6] = v;
  __syncthreads();
  if (tid == 0) out[0] = tmp[0] + tmp[1];
}

// ---------------------------------------------------------------------------
extern "C" void kernel_launch(void* const* d_in, const int* in_sizes, int n_in,
                              void* d_out, int out_size, void* d_ws, size_t ws_size,
                              hipStream_t stream) {
  const int* x = (const int*)d_in[0];
  const int* y = (const int*)d_in[1];
  const int* pre_tags = (const int*)d_in[2];
  const int* pinyin_tags = (const int*)d_in[3];
  const float* char_emb = (const float*)d_in[5];
  const float* tag_emb = (const float*)d_in[6];
  const float* pinyin_emb = (const float*)d_in[7];
  const float* w_ih_f = (const float*)d_in[8];
  const float* w_hh_f = (const float*)d_in[9];
  const float* b_ih_f = (const float*)d_in[10];
  const float* b_hh_f = (const float*)d_in[11];
  const float* w_ih_b = (const float*)d_in[12];
  const float* w_hh_b = (const float*)d_in[13];
  const float* b_ih_b = (const float*)d_in[14];
  const float* b_hh_b = (const float*)d_in[15];
  const float* w_out = (const float*)d_in[16];
  const float* b_out = (const float*)d_in[17];
  const float* start_trans = (const float*)d_in[18];
  const float* end_trans = (const float*)d_in[19];
  const float* trans = (const float*)d_in[20];

  char* ws = (char*)d_ws;
  __hip_bfloat16* char_proj = (__hip_bfloat16*)(ws);            // 10002*2048*2 = 40968192
  __hip_bfloat16* pin_proj = (__hip_bfloat16*)(ws + 40968192);  // 500*2048*2  = 2048000
  __hip_bfloat16* tag_proj = (__hip_bfloat16*)(ws + 43016192);  // 20*2048*2   = 81920
  __hip_bfloat16* h_glob = (__hip_bfloat16*)(ws + 43098112);    // 2*128*512*256*2 = 67108864
  float* em = (float*)(ws + 110206976);                         // 65536*20*4 = 5242880
  float* partials = (float*)(ws + 115449856);                   // 128*4

  proj_gemm<<<dim3(157, 8), 256, 0, stream>>>(char_emb, 10002, 300, 0, w_ih_f, w_ih_b,
                                              nullptr, nullptr, nullptr, nullptr, char_proj, 0);
  proj_gemm<<<dim3(8, 8), 256, 0, stream>>>(pinyin_emb, 500, 100, 300, w_ih_f, w_ih_b,
                                            nullptr, nullptr, nullptr, nullptr, pin_proj, 0);
  proj_gemm<<<dim3(1, 8), 256, 0, stream>>>(tag_emb, 20, 50, 400, w_ih_f, w_ih_b,
                                            b_ih_f, b_hh_f, b_ih_b, b_hh_b, tag_proj, 1);

  const int lstm_lds = 90624;  // 81920 planes + 8192 sidx + 512 hbuf
  hipFuncSetAttribute((const void*)lstm_kernel, hipFuncAttributeMaxDynamicSharedMemorySize,
                      lstm_lds);
  lstm_kernel<<<256, 256, lstm_lds, stream>>>(w_hh_f, w_hh_b, x, pinyin_tags, pre_tags,
                                              (const char*)char_proj, (const char*)pin_proj,
                                              (const char*)tag_proj, h_glob);

  emis_kernel<<<1024, 256, 0, stream>>>(h_glob, w_out, b_out, em);
  crf_kernel<<<128, 64, 0, stream>>>(em, y, start_trans, end_trans, trans, partials);
  reduce_kernel<<<1, 128, 0, stream>>>(partials, (float*)d_out);
}

// Round 9
// 1107.464 us; speedup vs baseline: 1.5074x; 1.0211x over previous
//
#include <hip/hip_runtime.h>
#include <hip/hip_bf16.h>

typedef __attribute__((ext_vector_type(8))) short short8;
typedef __attribute__((ext_vector_type(4))) float float4v;

#if __has_builtin(__builtin_amdgcn_sdot4)
#define DOT4(a, b, c) __builtin_amdgcn_sdot4((int)(a), (int)(b), (c), false)
#else
__device__ __forceinline__ int dot4_(int a, int b, int c) {
  c += (int)(signed char)(a) * (int)(signed char)(b);
  c += (int)(signed char)(a >> 8) * (int)(signed char)(b >> 8);
  c += (int)(signed char)(a >> 16) * (int)(signed char)(b >> 16);
  c += (a >> 24) * (b >> 24);
  return c;
}
#define DOT4(a, b, c) dot4_((int)(a), (int)(b), (c))
#endif

__device__ __forceinline__ float sigmoidf_(float x) {
  return __fdividef(1.f, 1.f + __expf(-x));
}
__device__ __forceinline__ float tanhf_(float x) {
  float e = __expf(2.f * x);
  return 1.f - __fdividef(2.f, e + 1.f);
}
__device__ __forceinline__ float bflo(unsigned int v) {
  return __uint_as_float(v << 16);
}
__device__ __forceinline__ float bfhi(unsigned int v) {
  return __uint_as_float(v & 0xffff0000u);
}

// quad (4-lane) butterflies via DPP quad_perm (VALU, not DS pipe)
template <int CTRL>
__device__ __forceinline__ int qadd_i(int v) {
  return v + __builtin_amdgcn_update_dpp(0, v, CTRL, 0xF, 0xF, true);
}
template <int CTRL>
__device__ __forceinline__ float qmax_f(float v) {
  int r = __builtin_amdgcn_update_dpp(0, __float_as_int(v), CTRL, 0xF, 0xF, true);
  return fmaxf(v, __int_as_float(r));
}
#define XOR1 0xB1  // quad_perm [1,0,3,2]
#define XOR2 0x4E  // quad_perm [2,3,0,1]

__device__ __forceinline__ unsigned int pack4_(float4 v, float inv) {
  int b0 = (int)rintf(v.x * inv), b1 = (int)rintf(v.y * inv);
  int b2 = (int)rintf(v.z * inv), b3 = (int)rintf(v.w * inv);
  return (unsigned int)((b0 & 0xff) | ((b1 & 0xff) << 8) | ((b2 & 0xff) << 16) |
                        ((b3 & 0xff) << 24));
}

// ---------------------------------------------------------------------------
// Kernel A: projected embedding tables.
// Logical col n in [0,2048): dir=n>>10, r=n&1023, gate=r>>8, u=r&255.
// Stored at out[m*2048 + dir*1024 + u*4 + gate]  ([row][dir][unit][i,f,g,o]).
// ---------------------------------------------------------------------------
__global__ __launch_bounds__(256) void proj_gemm(
    const float* __restrict__ A, int rowsA, int Kdim, int col_off,
    const float* __restrict__ wf, const float* __restrict__ wb,
    const float* __restrict__ bf1, const float* __restrict__ bf2,
    const float* __restrict__ bb1, const float* __restrict__ bb2,
    __hip_bfloat16* __restrict__ out, int add_bias) {
  __shared__ __align__(16) __hip_bfloat16 As[64][40];
  __shared__ __align__(16) __hip_bfloat16 Bs[256][40];
  const int tid = threadIdx.x;
  const int m0 = blockIdx.x * 64, n0 = blockIdx.y * 256;
  const int lane = tid & 63, wave = tid >> 6;
  const int quad = lane >> 4, lm = lane & 15;
  float4v acc[16] = {};
  const int ksteps = (Kdim + 31) >> 5;
  const int r = tid >> 2, c0 = (tid & 3) << 3;
  const int rb = tid >> 4, cb = (tid & 15) * 2;  // coalesced B staging
  for (int ks = 0; ks < ksteps; ++ks) {
    const int k0 = ks << 5;
#pragma unroll
    for (int e = 0; e < 8; ++e) {
      int kk = k0 + c0 + e;
      float av = (m0 + r < rowsA && kk < Kdim) ? A[(m0 + r) * Kdim + kk] : 0.f;
      As[r][c0 + e] = __float2bfloat16(av);
    }
#pragma unroll
    for (int j = 0; j < 16; ++j) {
      int n = n0 + rb + 16 * j;
      const float* __restrict__ wrow =
          (n < 1024) ? (wf + n * 450 + col_off) : (wb + (n - 1024) * 450 + col_off);
      int kk = k0 + cb;
      float b0 = 0.f, b1 = 0.f;
      if (kk < Kdim) {
        float2 v = *(const float2*)(wrow + kk);
        b0 = v.x;
        b1 = v.y;
      }
      Bs[rb + 16 * j][cb] = __float2bfloat16(b0);
      Bs[rb + 16 * j][cb + 1] = __float2bfloat16(b1);
    }
    __syncthreads();
    short8 af = *(const short8*)(&As[wave * 16 + lm][quad * 8]);
#pragma unroll
    for (int t = 0; t < 16; ++t) {
      short8 bf = *(const short8*)(&Bs[t * 16 + lm][quad * 8]);
      acc[t] = __builtin_amdgcn_mfma_f32_16x16x32_bf16(af, bf, acc[t], 0, 0, 0);
    }
    __syncthreads();
  }
#pragma unroll
  for (int t = 0; t < 16; ++t) {
#pragma unroll
    for (int rr = 0; rr < 4; ++rr) {
      int m = m0 + wave * 16 + quad * 4 + rr;
      int col = n0 + t * 16 + lm;
      if (m < rowsA) {
        float v = acc[t][rr];
        if (add_bias)
          v += (col < 1024) ? (bf1[col] + bf2[col]) : (bb1[col - 1024] + bb2[col - 1024]);
        int dir = col >> 10, r2 = col & 1023;
        int gate = r2 >> 8, u = r2 & 255;
        out[m * 2048 + dir * 1024 + u * 4 + gate] = __float2bfloat16(v);
      }
    }
  }
}

// ---------------------------------------------------------------------------
// Kernel B: BiLSTM recurrence, int8 dot4, 256 threads/chain (4 waves).
// Allocator law (7 data pts, R1-R8): VGPR budget = 2048/(2 x WG waves);
// 4-wave WG -> 256. Quad q owns units 4q..4q+3 (16 gate rows); lane e holds
// K-slice [64e,64e+64). 12 rows int8 in VGPRs (192 regs), 4 rows in LDS.
// LDS planes laid out [plane][chunk][lane] (uint4): every weight read is a
// lane-sequential b128 sweep -> ZERO bank conflicts (R8's 80 B-stride layout
// cost 5e7 conflict cycles). Plane offsets are compile-time immediates.
// ---------------------------------------------------------------------------
__global__ __launch_bounds__(256) void lstm_kernel(
    const float* __restrict__ whh_f, const float* __restrict__ whh_b,
    const int* __restrict__ x, const int* __restrict__ ptags, const int* __restrict__ gtags,
    const char* __restrict__ char_proj, const char* __restrict__ pin_proj,
    const char* __restrict__ tag_proj, __hip_bfloat16* __restrict__ h_out) {
  extern __shared__ __align__(16) char smem[];
  uint4* wlds = (uint4*)smem;                      // 16 slots x 256 lanes x 16 B = 65536
  int4* sidx = (int4*)(smem + 65536);              // 8192 B
  signed char* hb = (signed char*)(smem + 73728);  // 2*256 = 512 B

  const int tid = threadIdx.x;
  const int q = tid >> 2, e = tid & 3;
  const int chain = blockIdx.x;
  const int dir = chain >> 7;
  const int b = chain & 127;
  const float* __restrict__ whh = dir ? whh_b : whh_f;

  // stage index byte-offsets (table row pitch = 2048 bf16 = 4096 B)
  sidx[tid] = make_int4(x[b * 512 + tid] * 4096, ptags[b * 512 + tid] * 4096,
                        gtags[b * 512 + tid] * 4096, 0);
  sidx[tid + 256] = make_int4(x[b * 512 + tid + 256] * 4096, ptags[b * 512 + tid + 256] * 4096,
                              gtags[b * 512 + tid + 256] * 4096, 0);
  if (tid < 32) ((int4*)hb)[tid] = make_int4(0, 0, 0, 0);

  // ---- int8-quantize 16 gate rows (12 -> VGPR, 4 -> LDS planes) ----
  unsigned int Wreg[12][16];
  float sc4[4];
#pragma unroll
  for (int rr = 0; rr < 16; ++rr) {
    const int unit = 4 * q + (rr >> 2), gate = rr & 3;
    const float* __restrict__ wr = whh + (gate * 256 + unit) * 256 + e * 64;
    float mx = 0.f;
#pragma unroll
    for (int k4 = 0; k4 < 16; ++k4) {
      float4 v = ((const float4*)wr)[k4];
      mx = fmaxf(mx, fmaxf(fmaxf(fabsf(v.x), fabsf(v.y)), fmaxf(fabsf(v.z), fabsf(v.w))));
    }
    mx = qmax_f<XOR1>(mx);
    mx = qmax_f<XOR2>(mx);  // full-row max across the quad's 4 K-slices
    float inv = (mx > 0.f) ? __fdividef(127.f, mx) : 0.f;
    float scv = (mx > 0.f) ? (mx / (127.f * 127.f)) : 0.f;
    if ((rr >> 2) == e) sc4[gate] = scv;  // lane keeps scales of ITS unit
    if (rr < 12) {
#pragma unroll
      for (int k4 = 0; k4 < 16; ++k4) Wreg[rr][k4] = pack4_(((const float4*)wr)[k4], inv);
    } else {
      const int p = rr - 12;
#pragma unroll
      for (int c = 0; c < 4; ++c) {
        uint4 tv;
        tv.x = pack4_(((const float4*)wr)[c * 4 + 0], inv);
        tv.y = pack4_(((const float4*)wr)[c * 4 + 1], inv);
        tv.z = pack4_(((const float4*)wr)[c * 4 + 2], inv);
        tv.w = pack4_(((const float4*)wr)[c * 4 + 3], inv);
        wlds[(p * 4 + c) * 256 + tid] = tv;  // lane-sequential, conflict-free
      }
    }
  }
  __syncthreads();

  const int myu = tid;                       // 4q + e
  const int pre_off = dir * 2048 + myu * 8;  // bytes within a table row
  float cst = 0.f;
  const uint4* wbase = wlds + tid;  // + (p*4+c)*256 becomes a DS imm offset

  // prefetch step 0 pre-gates (all lanes: each owns one unit)
  int t_cur = dir ? 511 : 0;
  uint2 pc, pp, pt;
  {
    int4 ix = sidx[t_cur];
    pc = *(const uint2*)(char_proj + ix.x + pre_off);
    pp = *(const uint2*)(pin_proj + ix.y + pre_off);
    pt = *(const uint2*)(tag_proj + ix.z + pre_off);
  }

  for (int s = 0; s < 512; ++s) {
    const int t = t_cur;
    const uint2 cv = pc, pv = pp, gv = pt;
    const int tn = dir ? (t > 0 ? t - 1 : 0) : (t < 511 ? t + 1 : 511);
    t_cur = tn;
    {
      int4 ix = sidx[tn];
      pc = *(const uint2*)(char_proj + ix.x + pre_off);
      pp = *(const uint2*)(pin_proj + ix.y + pre_off);
      pt = *(const uint2*)(tag_proj + ix.z + pre_off);
    }

    const signed char* hbase = hb + (s & 1) * 256 + e * 64;
    int acc[16] = {0, 0, 0, 0, 0, 0, 0, 0, 0, 0, 0, 0, 0, 0, 0, 0};
#pragma unroll
    for (int c = 0; c < 4; ++c) {
      uint4 H = *(const uint4*)(hbase + c * 16);
#pragma unroll
      for (int rr = 0; rr < 12; ++rr) {
        acc[rr] = DOT4(Wreg[rr][4 * c + 0], H.x, acc[rr]);
        acc[rr] = DOT4(Wreg[rr][4 * c + 1], H.y, acc[rr]);
        acc[rr] = DOT4(Wreg[rr][4 * c + 2], H.z, acc[rr]);
        acc[rr] = DOT4(Wreg[rr][4 * c + 3], H.w, acc[rr]);
      }
#pragma unroll
      for (int p = 0; p < 4; ++p) {
        uint4 wv = wbase[(p * 4 + c) * 256];
        acc[12 + p] = DOT4(wv.x, H.x, acc[12 + p]);
        acc[12 + p] = DOT4(wv.y, H.y, acc[12 + p]);
        acc[12 + p] = DOT4(wv.z, H.z, acc[12 + p]);
        acc[12 + p] = DOT4(wv.w, H.w, acc[12 + p]);
      }
    }
    // quad butterfly: all 4 lanes get full-K sums for all 16 rows
#pragma unroll
    for (int rr = 0; rr < 16; ++rr) {
      int v = qadd_i<XOR1>(acc[rr]);
      acc[rr] = qadd_i<XOR2>(v);
    }
    // lane e picks its unit's rows (constant-index cndmask chains)
    int ai = e == 0 ? acc[0] : (e == 1 ? acc[4] : (e == 2 ? acc[8] : acc[12]));
    int af = e == 0 ? acc[1] : (e == 1 ? acc[5] : (e == 2 ? acc[9] : acc[13]));
    int ag = e == 0 ? acc[2] : (e == 1 ? acc[6] : (e == 2 ? acc[10] : acc[14]));
    int ao = e == 0 ? acc[3] : (e == 1 ? acc[7] : (e == 2 ? acc[11] : acc[15]));
    // pre-gates: (i,f) in .x, (g,o) in .y of each table's uint2
    float gi = bflo(cv.x) + bflo(pv.x) + bflo(gv.x) + (float)ai * sc4[0];
    float gf = bfhi(cv.x) + bfhi(pv.x) + bfhi(gv.x) + (float)af * sc4[1];
    float gg = bflo(cv.y) + bflo(pv.y) + bflo(gv.y) + (float)ag * sc4[2];
    float go = bfhi(cv.y) + bfhi(pv.y) + bfhi(gv.y) + (float)ao * sc4[3];
    cst = sigmoidf_(gf) * cst + sigmoidf_(gi) * tanhf_(gg);
    float hval = sigmoidf_(go) * tanhf_(cst);
    hb[((s + 1) & 1) * 256 + myu] = (signed char)(int)rintf(hval * 127.f);
    h_out[((size_t)chain * 512 + t) * 256 + myu] = __float2bfloat16(hval);
    __syncthreads();
  }
}

// ---------------------------------------------------------------------------
// Kernel C: emissions GEMM. em[b*512+t][k] = Hcat[n]·w_out[k] + b_out[k]
// ---------------------------------------------------------------------------
__global__ __launch_bounds__(256) void emis_kernel(
    const __hip_bfloat16* __restrict__ h_glob, const float* __restrict__ w_out,
    const float* __restrict__ b_out, float* __restrict__ em) {
  __shared__ __align__(16) __hip_bfloat16 As[64][40];
  __shared__ __align__(16) __hip_bfloat16 Bs[32][40];
  const int tid = threadIdx.x;
  const int n0 = blockIdx.x * 64;
  const int lane = tid & 63, wave = tid >> 6, quad = lane >> 4, lm = lane & 15;
  float4v acc[2] = {};
  const int r = tid >> 2, c0 = (tid & 3) << 3;
  const int rb = tid >> 3, cb = (tid & 7) << 2;
  for (int ks = 0; ks < 16; ++ks) {
    const int j0 = ks * 32;
    const int dirk = j0 >> 8, jin = j0 & 255;
    const int n = n0 + r, bb = n >> 9, tt = n & 511;
    const uint4* src =
        (const uint4*)(h_glob + ((size_t)(dirk * 128 + bb) * 512 + tt) * 256 + jin + c0);
    *(uint4*)(&As[r][c0]) = *src;
#pragma unroll
    for (int e = 0; e < 4; ++e) {
      float v = (rb < 20) ? w_out[rb * 512 + j0 + cb + e] : 0.f;
      Bs[rb][cb + e] = __float2bfloat16(v);
    }
    __syncthreads();
    short8 af = *(const short8*)(&As[wave * 16 + lm][quad * 8]);
#pragma unroll
    for (int t2 = 0; t2 < 2; ++t2) {
      short8 bf = *(const short8*)(&Bs[t2 * 16 + lm][quad * 8]);
      acc[t2] = __builtin_amdgcn_mfma_f32_16x16x32_bf16(af, bf, acc[t2], 0, 0, 0);
    }
    __syncthreads();
  }
#pragma unroll
  for (int t2 = 0; t2 < 2; ++t2) {
#pragma unroll
    for (int rr = 0; rr < 4; ++rr) {
      int col = t2 * 16 + lm;
      if (col < 20) {
        int n = n0 + wave * 16 + quad * 4 + rr;
        em[(size_t)n * 20 + col] = acc[t2][rr] + b_out[col];
      }
    }
  }
}

// ---------------------------------------------------------------------------
// Kernel D: CRF forward NLL. 1 wave per batch element.
// Single-wave block: alpha broadcast via v_readlane (no LDS, no barriers).
// ---------------------------------------------------------------------------
__global__ __launch_bounds__(64) void crf_kernel(
    const float* __restrict__ em, const int* __restrict__ y,
    const float* __restrict__ start_trans, const float* __restrict__ end_trans,
    const float* __restrict__ trans, float* __restrict__ partials) {
  const int b = blockIdx.x;
  const int lane = threadIdx.x;
  const int jj = lane < 20 ? lane : 19;
  const bool act = lane < 20;
  const float* __restrict__ emb = em + (size_t)b * 512 * 20;
  const int* __restrict__ yb = y + b * 512;

  // ---- gold-path score, parallel over t ----
  float s_part = 0.f;
#pragma unroll
  for (int i = 0; i < 8; ++i) {
    int t = lane + 64 * i;
    int yc = yb[t];
    float v = emb[t * 20 + yc];
    v += (t == 0) ? start_trans[yc] : trans[yb[t - 1] * 20 + yc];
    s_part += v;
  }
#pragma unroll
  for (int k = 32; k >= 1; k >>= 1) s_part += __shfl_xor(s_part, k, 64);
  float score = s_part + end_trans[yb[511]];

  // ---- forward algorithm ----
  float ET[20];
#pragma unroll
  for (int i = 0; i < 20; ++i) ET[i] = __expf(trans[i * 20 + jj]);
  float alpha = act ? (start_trans[jj] + emb[jj]) : -1e30f;
  float P = alpha;
#pragma unroll
  for (int k = 32; k >= 1; k >>= 1) P = fmaxf(P, __shfl_xor(P, k, 64));

  float eC = emb[1 * 20 + jj];
  float eN = emb[2 * 20 + jj];
  for (int t = 1; t < 512; ++t) {
    if ((t & 15) == 0) {
      P = alpha;
#pragma unroll
      for (int k = 32; k >= 1; k >>= 1) P = fmaxf(P, __shfl_xor(P, k, 64));
    }
    float ex = __expf(alpha - P);
    float s0 = 0.f, s1 = 0.f;
#pragma unroll
    for (int i = 0; i < 20; i += 2) {
      float e0 = __int_as_float(__builtin_amdgcn_readlane(__float_as_int(ex), i));
      float e1 = __int_as_float(__builtin_amdgcn_readlane(__float_as_int(ex), i + 1));
      s0 = fmaf(e0, ET[i], s0);
      s1 = fmaf(e1, ET[i + 1], s1);
    }
    int tf = t + 2 < 512 ? t + 2 : 511;
    float eF = emb[tf * 20 + jj];
    if (act) alpha = P + __logf(s0 + s1) + eC;
    eC = eN;
    eN = eF;
  }
  float v = act ? (alpha + end_trans[jj]) : -1e30f;
  float Pz = v;
#pragma unroll
  for (int k = 32; k >= 1; k >>= 1) Pz = fmaxf(Pz, __shfl_xor(Pz, k, 64));
  float e2 = __expf(v - Pz);
#pragma unroll
  for (int k = 32; k >= 1; k >>= 1) e2 += __shfl_xor(e2, k, 64);
  float logZ = Pz + __logf(e2);
  if (lane == 0) partials[b] = logZ - score;
}

__global__ __launch_bounds__(128) void reduce_kernel(const float* __restrict__ partials,
                                                     float* __restrict__ out) {
  const int tid = threadIdx.x;
  float v = partials[tid];
#pragma unroll
  for (int k = 32; k >= 1; k >>= 1) v += __shfl_xor(v, k, 64);
  __shared__ float tmp[2];
  if ((tid & 63) == 0) tmp[tid >> 6] = v;
  __syncthreads();
  if (tid == 0) out[0] = tmp[0] + tmp[1];
}

// ---------------------------------------------------------------------------
extern "C" void kernel_launch(void* const* d_in, const int* in_sizes, int n_in,
                              void* d_out, int out_size, void* d_ws, size_t ws_size,
                              hipStream_t stream) {
  const int* x = (const int*)d_in[0];
  const int* y = (const int*)d_in[1];
  const int* pre_tags = (const int*)d_in[2];
  const int* pinyin_tags = (const int*)d_in[3];
  const float* char_emb = (const float*)d_in[5];
  const float* tag_emb = (const float*)d_in[6];
  const float* pinyin_emb = (const float*)d_in[7];
  const float* w_ih_f = (const float*)d_in[8];
  const float* w_hh_f = (const float*)d_in[9];
  const float* b_ih_f = (const float*)d_in[10];
  const float* b_hh_f = (const float*)d_in[11];
  const float* w_ih_b = (const float*)d_in[12];
  const float* w_hh_b = (const float*)d_in[13];
  const float* b_ih_b = (const float*)d_in[14];
  const float* b_hh_b = (const float*)d_in[15];
  const float* w_out = (const float*)d_in[16];
  const float* b_out = (const float*)d_in[17];
  const float* start_trans = (const float*)d_in[18];
  const float* end_trans = (const float*)d_in[19];
  const float* trans = (const float*)d_in[20];

  char* ws = (char*)d_ws;
  __hip_bfloat16* char_proj = (__hip_bfloat16*)(ws);            // 10002*2048*2 = 40968192
  __hip_bfloat16* pin_proj = (__hip_bfloat16*)(ws + 40968192);  // 500*2048*2  = 2048000
  __hip_bfloat16* tag_proj = (__hip_bfloat16*)(ws + 43016192);  // 20*2048*2   = 81920
  __hip_bfloat16* h_glob = (__hip_bfloat16*)(ws + 43098112);    // 2*128*512*256*2 = 67108864
  float* em = (float*)(ws + 110206976);                         // 65536*20*4 = 5242880
  float* partials = (float*)(ws + 115449856);                   // 128*4

  proj_gemm<<<dim3(157, 8), 256, 0, stream>>>(char_emb, 10002, 300, 0, w_ih_f, w_ih_b,
                                              nullptr, nullptr, nullptr, nullptr, char_proj, 0);
  proj_gemm<<<dim3(8, 8), 256, 0, stream>>>(pinyin_emb, 500, 100, 300, w_ih_f, w_ih_b,
                                            nullptr, nullptr, nullptr, nullptr, pin_proj, 0);
  proj_gemm<<<dim3(1, 8), 256, 0, stream>>>(tag_emb, 20, 50, 400, w_ih_f, w_ih_b,
                                            b_ih_f, b_hh_f, b_ih_b, b_hh_b, tag_proj, 1);

  const int lstm_lds = 74240;  // 65536 planes + 8192 sidx + 512 hbuf
  hipFuncSetAttribute((const void*)lstm_kernel, hipFuncAttributeMaxDynamicSharedMemorySize,
                      lstm_lds);
  lstm_kernel<<<256, 256, lstm_lds, stream>>>(w_hh_f, w_hh_b, x, pinyin_tags, pre_tags,
                                              (const char*)char_proj, (const char*)pin_proj,
                                              (const char*)tag_proj, h_glob);

  emis_kernel<<<1024, 256, 0, stream>>>(h_glob, w_out, b_out, em);
  crf_kernel<<<128, 64, 0, stream>>>(em, y, start_trans, end_trans, trans, partials);
  reduce_kernel<<<1, 128, 0, stream>>>(partials, (float*)d_out);
}